// Round 12
// baseline (1273.688 us; speedup 1.0000x reference)
//
#include <hip/hip_runtime.h>
#include <math.h>

#define N_NODES   100000
#define N_EDGES   200000
#define NNZ       2000000
#define K_KEEP    1000000
#define BANDCAP   131072
#define TIECAP    4096
#define DELTA     1.0e-3f
#define SCAN_BLOCKS 196   // ceil(200000/1024)
#define USCALE (4294967296.0 / 4.0e-3)   // band key -> u32 map; band width < 4e-3 guaranteed

// ---------------- workspace layout (bytes) ----------------
#define OFF_PAB   ((size_t)0)          // float2 p_ab2 [N_NODES*32] 25,600,000 (.x=a_vk, .y=b_vk)
#define OFF_PB32  ((size_t)25600000)   // f32 probs_b [NNZ]        8,000,000 (CSR/p-order probs)
#define OFF_VJ    ((size_t)33600000)   // uint2 vj [NNZ]          16,000,000 (.x=vertex, .y=orig j)
#define OFF_POS   ((size_t)49600000)   // u32 pos [NNZ] j->p       8,000,000
#define OFF_EOFF  ((size_t)57600000)   // u32 edge_off [N_EDGES]     800,000
#define OFF_CUR   ((size_t)58400000)   // u32 cursor [N_EDGES]       800,000
#define OFF_BS    ((size_t)59200000)   // u32 bsums [256]              1,024
#define OFF_BANDP ((size_t)59201024)   // u32 band_p [BANDCAP]       524,288
#define OFF_BANDJ ((size_t)59725312)   // u32 band_j [BANDCAP]       524,288
#define OFF_BANDE ((size_t)60249600)   // u32 band_e [BANDCAP]       524,288
#define OFF_BANDV ((size_t)60773888)   // u32 band_v [BANDCAP]       524,288
#define OFF_BANDK ((size_t)61298176)   // u64 band_key [BANDCAP]   1,048,576
#define OFF_TIEK  ((size_t)62346752)   // u64 tie_k [TIECAP]          32,768
#define OFF_TIEJ  ((size_t)62379520)   // u32 tie_j [TIECAP]          16,384
#define OFF_TIEP  ((size_t)62395904)   // u32 tie_p [TIECAP]          16,384
// --- zero region ---
#define OFF_FLAG  ((size_t)62412288)   // u8  flag [NNZ]           2,000,000 (0 none, 2 selected)
#define OFF_ECNT  ((size_t)64412288)   // u32 edge_cnt [N_EDGES]     800,000
#define OFF_HIST  ((size_t)65212288)   // u32 hist [4*2048]           32,768
#define OFF_ST    ((size_t)65245056)   // SelState                        64
#define ZERO_OFF  OFF_FLAG
#define ZERO_LEN  ((size_t)(65245120 - 62412288))

struct SelState {
    unsigned int B1;        // f32 pass-1 bucket
    unsigned int rem1;      // remaining rank within B1
    float lo_edge, hi_edge; // band boundaries
    unsigned int n_hi;      // count of f32 probs > hi_edge
    unsigned int band_n;    // band append counter
    unsigned int bB1;       // band-select pass-1 bucket (u32 map, bits 31:21)
    unsigned int brem1;     // remaining rank within bB1
    unsigned int bU0;       // threshold u-bucket base (width 1024)
    unsigned int brem2;     // remaining rank within the u-bucket
    unsigned int tie_n;     // tie-bucket append counter
};

__device__ __forceinline__ unsigned int band_u32(double key, float lo) {
    double t = (key - (double)lo) * USCALE;
    t = t < 0.0 ? 0.0 : (t > 4294967295.0 ? 4294967295.0 : t);
    return (unsigned int)t;   // monotone non-decreasing in key
}

// p_ab2[v][k] = (sum_d x[v][d]*W1[d][k], sum_d x[v][d]*W1[64+d][k])
__global__ void proj_kernel(const float* __restrict__ x, const float* __restrict__ W1,
                            float2* __restrict__ p_ab2) {
    __shared__ float sW[128 * 32];
    __shared__ float sx[8][64];
    for (int t = threadIdx.x; t < 128 * 32; t += 256) sW[t] = W1[t];
    int base = blockIdx.x * 8;
    for (int t = threadIdx.x; t < 512; t += 256) {
        int n = t >> 6, d = t & 63;
        int g = base + n;
        sx[n][d] = (g < N_NODES) ? x[(size_t)g * 64 + d] : 0.f;
    }
    __syncthreads();
    int ln = threadIdx.x >> 5;
    int k  = threadIdx.x & 31;
    int node = base + ln;
    if (node >= N_NODES) return;
    float sa = 0.f, sb = 0.f;
    for (int d = 0; d < 64; ++d) {
        float xv = sx[ln][d];
        sa += xv * sW[d * 32 + k];
        sb += xv * sW[(64 + d) * 32 + k];
    }
    p_ab2[(size_t)node * 32 + k] = make_float2(sa, sb);
}

// ---------------- CSR build ----------------
__global__ void count_kernel(const int* __restrict__ E, unsigned int* __restrict__ edge_cnt) {
    int j = blockIdx.x * 256 + threadIdx.x;
    if (j >= NNZ) return;
    atomicAdd(&edge_cnt[E[j]], 1u);
}

__global__ void scanA_kernel(const unsigned int* __restrict__ edge_cnt,
                             unsigned int* __restrict__ edge_off, unsigned int* __restrict__ bsums) {
    __shared__ unsigned int s[256];
    int tid = threadIdx.x;
    int base = blockIdx.x * 1024 + tid * 4;
    unsigned int v0 = (base + 0 < N_EDGES) ? edge_cnt[base + 0] : 0u;
    unsigned int v1 = (base + 1 < N_EDGES) ? edge_cnt[base + 1] : 0u;
    unsigned int v2 = (base + 2 < N_EDGES) ? edge_cnt[base + 2] : 0u;
    unsigned int v3 = (base + 3 < N_EDGES) ? edge_cnt[base + 3] : 0u;
    unsigned int tsum = v0 + v1 + v2 + v3;
    s[tid] = tsum;
    __syncthreads();
    for (int off = 1; off < 256; off <<= 1) {
        unsigned int t = (tid >= off) ? s[tid - off] : 0u;
        __syncthreads();
        s[tid] += t;
        __syncthreads();
    }
    unsigned int excl = s[tid] - tsum;
    if (base + 0 < N_EDGES) edge_off[base + 0] = excl;
    if (base + 1 < N_EDGES) edge_off[base + 1] = excl + v0;
    if (base + 2 < N_EDGES) edge_off[base + 2] = excl + v0 + v1;
    if (base + 3 < N_EDGES) edge_off[base + 3] = excl + v0 + v1 + v2;
    if (tid == 255) bsums[blockIdx.x] = s[255];
}

__global__ void scanB_kernel(unsigned int* __restrict__ bsums) {
    __shared__ unsigned int s[256];
    int tid = threadIdx.x;
    unsigned int v = (tid < SCAN_BLOCKS) ? bsums[tid] : 0u;
    s[tid] = v;
    __syncthreads();
    for (int off = 1; off < 256; off <<= 1) {
        unsigned int t = (tid >= off) ? s[tid - off] : 0u;
        __syncthreads();
        s[tid] += t;
        __syncthreads();
    }
    if (tid < SCAN_BLOCKS) bsums[tid] = s[tid] - v;
}

__global__ void scanC_kernel(unsigned int* __restrict__ edge_off, const unsigned int* __restrict__ bsums,
                             unsigned int* __restrict__ cursor) {
    int i = blockIdx.x * 256 + threadIdx.x;
    if (i >= N_EDGES) return;
    unsigned int o = edge_off[i] + bsums[i >> 10];
    edge_off[i] = o;
    cursor[i] = o;
}

// 8 incidences/thread: 8 independent atomic returns in flight (hide far-atomic latency)
__global__ void bucket_kernel(const int* __restrict__ V, const int* __restrict__ E,
                              unsigned int* __restrict__ cursor,
                              uint2* __restrict__ vj, unsigned int* __restrict__ pos) {
    unsigned int base = blockIdx.x * 2048 + threadIdx.x;
    int ev[8], vv[8];
    unsigned int pp[8];
    #pragma unroll
    for (int c = 0; c < 8; ++c) {
        unsigned int j = base + 256u * c;
        if (j < NNZ) { ev[c] = E[j]; vv[c] = V[j]; }
    }
    #pragma unroll
    for (int c = 0; c < 8; ++c) {
        unsigned int j = base + 256u * c;
        if (j < NNZ) pp[c] = atomicAdd(&cursor[ev[c]], 1u);
    }
    #pragma unroll
    for (int c = 0; c < 8; ++c) {
        unsigned int j = base + 256u * c;
        if (j < NNZ) {
            vj[pp[c]] = make_uint2((unsigned int)vv[c], j);
            pos[j] = pp[c];
        }
    }
}

// ---------------- fused per-edge mean + per-incidence MLP + level-1 histogram ----------------
// grid is exactly N_EDGES/4 blocks (200000 % 4 == 0): every wave has a valid edge,
// so the block-level __syncthreads around the LDS histogram are safe.
__global__ void edge_logit_kernel(const uint2* __restrict__ vj,
                                  const unsigned int* __restrict__ edge_off,
                                  const unsigned int* __restrict__ edge_cnt,
                                  const float2* __restrict__ p_ab2,
                                  const float* __restrict__ b1, const float* __restrict__ W2,
                                  const float* __restrict__ b2,
                                  float* __restrict__ probs_b, float* __restrict__ o_ep,
                                  unsigned int* __restrict__ hist) {
    __shared__ float sa[4][32 * 32];   // 16 KB: [wave][slot i][k]
    __shared__ float slog[4][32];      // per-incidence logits
    __shared__ unsigned int lhist[2048];
    for (int t = threadIdx.x; t < 2048; t += 256) lhist[t] = 0;
    __syncthreads();

    int e = blockIdx.x * 4 + (threadIdx.x >> 6);
    int w    = threadIdx.x >> 6;
    int lane = threadIdx.x & 63;
    int k    = lane & 31;
    unsigned int half = (unsigned int)(lane >> 5);

    unsigned int off = edge_off[e];
    unsigned int deg = edge_cnt[e];
    unsigned int mind = deg < 32u ? deg : 32u;

    // coalesced member-id preload (lanes 0..mind-1)
    unsigned int myv = ((unsigned int)lane < mind) ? vj[off + lane].x : 0u;

    float bacc = 0.f;
    for (unsigned int i = half; i < mind; i += 2u) {
        unsigned int v = (unsigned int)__shfl((int)myv, (int)i, 64);
        float2 r = p_ab2[(size_t)v * 32u + k];
        sa[w][i * 32 + k] = r.x;
        bacc += r.y;
    }
    for (unsigned int i = 32u + half; i < deg; i += 2u) {   // deg>32 tail: b only
        unsigned int v = vj[off + i].x;
        bacc += p_ab2[(size_t)v * 32u + k].y;
    }

    float cc  = (float)(deg > 1u ? deg : 1u);
    float emk = (bacc + __shfl_xor(bacc, 32)) / cc + b1[k];
    float w2k = W2[k];
    float b2v = b2[0];
    float prsum = 0.f;

    for (unsigned int i = half; i < mind; i += 2u) {
        float hk = sa[w][i * 32 + k] + emk;
        hk = hk > 0.f ? hk : 0.f;
        float t = hk * w2k;
        #pragma unroll
        for (int o = 16; o > 0; o >>= 1) t += __shfl_down(t, o, 32);
        if (k == 0) slog[w][i] = t;
    }
    // vectorized epilogue: lane i <-> incidence i (same wave; LDS ops in order)
    if ((unsigned int)lane < mind) {
        float pr = 1.f / (1.f + __expf(-(slog[w][lane] + b2v)));
        probs_b[off + lane] = pr;      // coalesced
        prsum = pr;
        atomicAdd(&lhist[__float_as_uint(pr) >> 21], 1u);
    }
    for (unsigned int i = 32u + half; i < deg; i += 2u) {   // deg>32 tail: a from global
        unsigned int v = vj[off + i].x;
        float hk = p_ab2[(size_t)v * 32u + k].x + emk;
        hk = hk > 0.f ? hk : 0.f;
        float t = hk * w2k;
        #pragma unroll
        for (int o = 16; o > 0; o >>= 1) t += __shfl_down(t, o, 32);
        if (k == 0) {
            float pr = 1.f / (1.f + __expf(-(t + b2v)));
            probs_b[off + i] = pr;
            prsum += pr;
            atomicAdd(&lhist[__float_as_uint(pr) >> 21], 1u);
        }
    }
    #pragma unroll
    for (int o = 32; o > 0; o >>= 1) prsum += __shfl_down(prsum, o, 64);
    if (lane == 0) o_ep[e] = prsum / cc;

    __syncthreads();
    for (int t = threadIdx.x; t < 2048; t += 256)
        if (lhist[t]) atomicAdd(&hist[t], lhist[t]);
}

// ---------------- level-2 histogram on f32 keys ----------------
__global__ void hist2_kernel(const float* __restrict__ probs_b, const SelState* __restrict__ st,
                             unsigned int* __restrict__ hist) {
    __shared__ unsigned int lh[2048];
    for (int t = threadIdx.x; t < 2048; t += 256) lh[t] = 0;
    __syncthreads();
    unsigned int B1 = st->B1;
    for (unsigned int i = blockIdx.x * 256 + threadIdx.x; i < NNZ; i += gridDim.x * 256) {
        unsigned int key = __float_as_uint(probs_b[i]);
        if ((key >> 21) == B1) atomicAdd(&lh[(key >> 10) & 2047u], 1u);
    }
    __syncthreads();
    for (int t = threadIdx.x; t < 2048; t += 256)
        if (lh[t]) atomicAdd(&hist[2048 + t], lh[t]);
}

// which=0: select bucket B1 at rank K_KEEP; which=1: select B2 at rank rem1, set band edges
__global__ void scan_sel_kernel(const unsigned int* __restrict__ hist, SelState* __restrict__ st, int which) {
    __shared__ unsigned int csum[256];
    int t = threadIdx.x;
    unsigned int target = (which == 0) ? (unsigned int)K_KEEP : st->rem1;
    const unsigned int* h = hist + (which ? 2048 : 0);
    unsigned int b[8];
    unsigned int s = 0;
    #pragma unroll
    for (int i = 0; i < 8; ++i) { b[i] = h[t * 8 + i]; s += b[i]; }
    csum[t] = s;
    __syncthreads();
    for (int off = 1; off < 256; off <<= 1) {
        unsigned int v = (t + off < 256) ? csum[t + off] : 0u;
        __syncthreads();
        csum[t] += v;
        __syncthreads();
    }
    unsigned int above = csum[t] - s;       // sum over chunks > t
    if (above < target && target <= above + s) {
        unsigned int rem = target - above;
        unsigned int cum = 0;
        #pragma unroll
        for (int i = 7; i >= 0; --i) {
            if (rem <= cum + b[i]) {
                unsigned int bin = (unsigned int)(t * 8 + i);
                if (which == 0) { st->B1 = bin; st->rem1 = rem - cum; }
                else {
                    unsigned int P = (st->B1 << 21) | (bin << 10);
                    st->lo_edge = __uint_as_float(P) - DELTA;
                    st->hi_edge = __uint_as_float(P + 1024u) + DELTA;
                }
                break;
            }
            cum += b[i];
        }
    }
}

// fused: count n_hi + LDS-aggregated band append, single coalesced probs pass
__global__ void bandsel_kernel(const float* __restrict__ probs_b, const int* __restrict__ E,
                               const uint2* __restrict__ vj,
                               SelState* __restrict__ st,
                               unsigned int* __restrict__ band_p, unsigned int* __restrict__ band_j,
                               unsigned int* __restrict__ band_e, unsigned int* __restrict__ band_v) {
    __shared__ unsigned int scnt, sbase, hicnt;
    if (threadIdx.x == 0) { scnt = 0; hicnt = 0; }
    __syncthreads();
    unsigned int p = blockIdx.x * 256 + threadIdx.x;
    float hi = st->hi_edge, lo = st->lo_edge;
    bool valid = p < NNZ;
    float pk = valid ? probs_b[p] : -1.f;
    bool ishi = pk > hi;
    bool isband = valid && !ishi && pk >= lo;
    unsigned long long m = __ballot(ishi);
    if ((threadIdx.x & 63) == 0 && m) atomicAdd(&hicnt, (unsigned int)__popcll(m));
    unsigned int local = 0;
    if (isband) local = atomicAdd(&scnt, 1u);     // LDS atomic: on-CU, fast
    __syncthreads();
    if (threadIdx.x == 0) {
        if (scnt) sbase = atomicAdd(&st->band_n, scnt);
        if (hicnt) atomicAdd(&st->n_hi, hicnt);
    }
    __syncthreads();
    if (isband) {
        unsigned int s = sbase + local;
        if (s < BANDCAP) {
            uint2 t = vj[p];
            band_p[s] = p;
            band_j[s] = t.y;
            band_e[s] = (unsigned int)E[t.y];
            band_v[s] = t.x;
        }
    }
}

// exact f64 recompute for band members; W1 staged in LDS
__global__ void rescue_kernel(const uint2* __restrict__ vj,
                              const unsigned int* __restrict__ edge_off,
                              const unsigned int* __restrict__ edge_cnt,
                              const float* __restrict__ x, const float* __restrict__ W1,
                              const float* __restrict__ b1, const float* __restrict__ W2,
                              const float* __restrict__ b2,
                              const unsigned int* __restrict__ band_e,
                              const unsigned int* __restrict__ band_v,
                              const SelState* __restrict__ st,
                              unsigned long long* __restrict__ band_key) {
    unsigned int n = st->band_n; if (n > BANDCAP) n = BANDCAP;
    if (blockIdx.x * 8 >= n) return;
    __shared__ float sW[128 * 32];
    for (int t = threadIdx.x; t < 128 * 32; t += 256) sW[t] = W1[t];
    __syncthreads();
    unsigned int g = blockIdx.x * 8 + (threadIdx.x >> 5);
    if (g >= n) return;
    int k = threadIdx.x & 31;
    unsigned int v = band_v[g];
    unsigned int e = band_e[g];
    unsigned int off = edge_off[e];
    unsigned int deg = edge_cnt[e];

    const float* xv = x + (size_t)v * 64u;
    double a = 0.0;
    #pragma unroll 8
    for (int d = 0; d < 64; ++d) a += (double)xv[d] * (double)sW[d * 32 + k];
    double bsum = 0.0;
    for (unsigned int m = off; m < off + deg; ++m) {
        const float* xm = x + (size_t)vj[m].x * 64u;
        double acc = 0.0;
        #pragma unroll 8
        for (int d = 0; d < 64; ++d) acc += (double)xm[d] * (double)sW[(64 + d) * 32 + k];
        bsum += acc;
    }
    double cc = (double)(deg > 1u ? deg : 1u);
    double h = a + bsum / cc + (double)b1[k];
    h = h > 0.0 ? h : 0.0;
    double t = h * (double)W2[k];
    #pragma unroll
    for (int o = 16; o > 0; o >>= 1) t += __shfl_down(t, o, 32);
    if (k == 0) {
        double pr = 1.0 / (1.0 + exp(-(t + (double)b2[0])));
        band_key[g] = (unsigned long long)__double_as_longlong(pr);
    }
}

// ---------------- O(n) band selection: 2-level hist on monotone u32 map ----------------
__global__ void bhist1_kernel(const unsigned long long* __restrict__ band_key,
                              const SelState* __restrict__ st, unsigned int* __restrict__ hist) {
    __shared__ unsigned int lh[2048];
    for (int t = threadIdx.x; t < 2048; t += 256) lh[t] = 0;
    __syncthreads();
    unsigned int n = st->band_n; if (n > BANDCAP) n = BANDCAP;
    float lo = st->lo_edge;
    for (unsigned int i = blockIdx.x * 256 + threadIdx.x; i < n; i += gridDim.x * 256) {
        unsigned int u = band_u32(__longlong_as_double((long long)band_key[i]), lo);
        atomicAdd(&lh[u >> 21], 1u);
    }
    __syncthreads();
    for (int t = threadIdx.x; t < 2048; t += 256)
        if (lh[t]) atomicAdd(&hist[4096 + t], lh[t]);
}

__global__ void bhist2_kernel(const unsigned long long* __restrict__ band_key,
                              const SelState* __restrict__ st, unsigned int* __restrict__ hist) {
    __shared__ unsigned int lh[2048];
    for (int t = threadIdx.x; t < 2048; t += 256) lh[t] = 0;
    __syncthreads();
    unsigned int n = st->band_n; if (n > BANDCAP) n = BANDCAP;
    float lo = st->lo_edge;
    unsigned int bB1 = st->bB1;
    for (unsigned int i = blockIdx.x * 256 + threadIdx.x; i < n; i += gridDim.x * 256) {
        unsigned int u = band_u32(__longlong_as_double((long long)band_key[i]), lo);
        if ((u >> 21) == bB1) atomicAdd(&lh[(u >> 10) & 2047u], 1u);
    }
    __syncthreads();
    for (int t = threadIdx.x; t < 2048; t += 256)
        if (lh[t]) atomicAdd(&hist[6144 + t], lh[t]);
}

// which=0: bucket bB1 at rank (K_KEEP - n_hi); which=1: bucket bB2 at rank brem1 -> bU0, brem2
__global__ void bscan_kernel(const unsigned int* __restrict__ hist, SelState* __restrict__ st, int which) {
    __shared__ unsigned int csum[256];
    int t = threadIdx.x;
    unsigned int target = (which == 0) ? ((unsigned int)K_KEEP - st->n_hi) : st->brem1;
    const unsigned int* h = hist + (which ? 6144 : 4096);
    unsigned int b[8];
    unsigned int s = 0;
    #pragma unroll
    for (int i = 0; i < 8; ++i) { b[i] = h[t * 8 + i]; s += b[i]; }
    csum[t] = s;
    __syncthreads();
    for (int off = 1; off < 256; off <<= 1) {
        unsigned int v = (t + off < 256) ? csum[t + off] : 0u;
        __syncthreads();
        csum[t] += v;
        __syncthreads();
    }
    unsigned int above = csum[t] - s;
    if (above < target && target <= above + s) {
        unsigned int rem = target - above;
        unsigned int cum = 0;
        #pragma unroll
        for (int i = 7; i >= 0; --i) {
            if (rem <= cum + b[i]) {
                unsigned int bin = (unsigned int)(t * 8 + i);
                if (which == 0) { st->bB1 = bin; st->brem1 = rem - cum; }
                else            { st->bU0 = (st->bB1 << 21) | (bin << 10); st->brem2 = rem - cum; }
                break;
            }
            cum += b[i];
        }
    }
}

// mark u >= bU0+1024 selected; collect tie bucket [bU0, bU0+1024)
__global__ void btie_kernel(const unsigned long long* __restrict__ band_key,
                            const unsigned int* __restrict__ band_j,
                            const unsigned int* __restrict__ band_p,
                            SelState* __restrict__ st, unsigned char* __restrict__ flag,
                            unsigned long long* __restrict__ tie_k,
                            unsigned int* __restrict__ tie_j, unsigned int* __restrict__ tie_p) {
    unsigned int n = st->band_n; if (n > BANDCAP) n = BANDCAP;
    unsigned int i = blockIdx.x * 256 + threadIdx.x;
    if (i >= n) return;
    float lo = st->lo_edge;
    unsigned int U0 = st->bU0;
    unsigned long long key = band_key[i];
    unsigned int u = band_u32(__longlong_as_double((long long)key), lo);
    if (u >= U0 + 1024u) {
        flag[band_p[i]] = 2u;
    } else if (u >= U0) {
        unsigned int s = atomicAdd(&st->tie_n, 1u);
        if (s < TIECAP) { tie_k[s] = key; tie_j[s] = band_j[i]; tie_p[s] = band_p[i]; }
    }
}

// exact rank inside the (tiny) tie bucket by (key desc, j asc); take first brem2
__global__ void btierank_kernel(const unsigned long long* __restrict__ tie_k,
                                const unsigned int* __restrict__ tie_j,
                                const unsigned int* __restrict__ tie_p,
                                const SelState* __restrict__ st, unsigned char* __restrict__ flag) {
    unsigned int n = st->tie_n; if (n > TIECAP) n = TIECAP;
    unsigned int need = st->brem2;
    for (unsigned int i = threadIdx.x; i < n; i += 256) {
        unsigned long long ki = tie_k[i];
        unsigned int ji = tie_j[i];
        unsigned int r = 0;
        for (unsigned int q = 0; q < n; ++q) {
            unsigned long long kq = tie_k[q];
            if (kq > ki || (kq == ki && tie_j[q] < ji)) r++;
        }
        if (r < need) flag[tie_p[i]] = 2u;
    }
}

// j-order coalesced outputs; hard bit computed inline from gathered probs/flag
__global__ void out_kernel(const float* __restrict__ probs_b, const unsigned char* __restrict__ flag,
                           const unsigned int* __restrict__ pos, const SelState* __restrict__ st,
                           float* __restrict__ o_probs, float* __restrict__ o_soft, float* __restrict__ o_hard) {
    unsigned int j = blockIdx.x * 256 + threadIdx.x;
    if (j >= NNZ) return;
    float hi = st->hi_edge;
    unsigned int p = pos[j];
    float pk = probs_b[p];
    float hb = (pk > hi || flag[p] == 2u) ? 1.f : 0.f;
    o_probs[j] = pk;
    o_soft[j]  = hb;
    o_hard[j]  = hb;
}

// per-edge: edge_soft / edge_hard recomputed from CSR-coalesced probs/flag
__global__ void edge_out_kernel(const float* __restrict__ probs_b, const unsigned char* __restrict__ flag,
                                const unsigned int* __restrict__ edge_off,
                                const unsigned int* __restrict__ edge_cnt,
                                const SelState* __restrict__ st,
                                float* __restrict__ o_es, float* __restrict__ o_eh) {
    unsigned int e = blockIdx.x * 256 + threadIdx.x;
    if (e >= N_EDGES) return;
    float hi = st->hi_edge;
    unsigned int off = edge_off[e], deg = edge_cnt[e];
    unsigned int cnt = 0;
    for (unsigned int i = 0; i < deg; ++i)
        cnt += (probs_b[off + i] > hi || flag[off + i] == 2u) ? 1u : 0u;
    float cc = (float)(deg > 1u ? deg : 1u);
    o_es[e] = (float)cnt / cc;
    o_eh[e] = cnt ? 1.f : 0.f;
}

extern "C" void kernel_launch(void* const* d_in, const int* in_sizes, int n_in,
                              void* d_out, int out_size, void* d_ws, size_t ws_size,
                              hipStream_t stream) {
    const float* x  = (const float*)d_in[0];
    const int*   V  = (const int*)d_in[1];
    const int*   E  = (const int*)d_in[2];
    const float* W1 = (const float*)d_in[3];
    const float* b1 = (const float*)d_in[4];
    const float* W2 = (const float*)d_in[5];
    const float* b2 = (const float*)d_in[6];

    float* out     = (float*)d_out;
    float* o_probs = out;
    float* o_soft  = out + NNZ;
    float* o_hard  = out + 2 * (size_t)NNZ;
    float* o_ep    = out + 3 * (size_t)NNZ;
    float* o_es    = out + 3 * (size_t)NNZ + N_EDGES;
    float* o_eh    = out + 3 * (size_t)NNZ + 2 * (size_t)N_EDGES;

    char* w = (char*)d_ws;
    float2*             p_ab2    = (float2*)(w + OFF_PAB);
    float*              probs_b  = (float*)(w + OFF_PB32);
    uint2*              vj       = (uint2*)(w + OFF_VJ);
    unsigned int*       pos      = (unsigned int*)(w + OFF_POS);
    unsigned int*       edge_off = (unsigned int*)(w + OFF_EOFF);
    unsigned int*       cursor   = (unsigned int*)(w + OFF_CUR);
    unsigned int*       bsums    = (unsigned int*)(w + OFF_BS);
    unsigned int*       band_p   = (unsigned int*)(w + OFF_BANDP);
    unsigned int*       band_j   = (unsigned int*)(w + OFF_BANDJ);
    unsigned int*       band_e   = (unsigned int*)(w + OFF_BANDE);
    unsigned int*       band_v   = (unsigned int*)(w + OFF_BANDV);
    unsigned long long* band_key = (unsigned long long*)(w + OFF_BANDK);
    unsigned long long* tie_k    = (unsigned long long*)(w + OFF_TIEK);
    unsigned int*       tie_j    = (unsigned int*)(w + OFF_TIEJ);
    unsigned int*       tie_p    = (unsigned int*)(w + OFF_TIEP);
    unsigned char*      flag     = (unsigned char*)(w + OFF_FLAG);
    unsigned int*       edge_cnt = (unsigned int*)(w + OFF_ECNT);
    unsigned int*       hist     = (unsigned int*)(w + OFF_HIST);
    SelState*           st       = (SelState*)(w + OFF_ST);

    hipMemsetAsync(w + ZERO_OFF, 0, ZERO_LEN, stream);

    proj_kernel<<<(N_NODES + 7) / 8, 256, 0, stream>>>(x, W1, p_ab2);

    count_kernel<<<(NNZ + 255) / 256, 256, 0, stream>>>(E, edge_cnt);
    scanA_kernel<<<SCAN_BLOCKS, 256, 0, stream>>>(edge_cnt, edge_off, bsums);
    scanB_kernel<<<1, 256, 0, stream>>>(bsums);
    scanC_kernel<<<(N_EDGES + 255) / 256, 256, 0, stream>>>(edge_off, bsums, cursor);
    bucket_kernel<<<(NNZ + 2047) / 2048, 256, 0, stream>>>(V, E, cursor, vj, pos);

    edge_logit_kernel<<<N_EDGES / 4, 256, 0, stream>>>(vj, edge_off, edge_cnt,
                                                       p_ab2, b1, W2, b2, probs_b, o_ep, hist);

    scan_sel_kernel<<<1, 256, 0, stream>>>(hist, st, 0);
    hist2_kernel<<<1024, 256, 0, stream>>>(probs_b, st, hist);
    scan_sel_kernel<<<1, 256, 0, stream>>>(hist, st, 1);

    bandsel_kernel<<<(NNZ + 255) / 256, 256, 0, stream>>>(probs_b, E, vj, st,
                                                          band_p, band_j, band_e, band_v);
    rescue_kernel<<<BANDCAP / 8, 256, 0, stream>>>(vj, edge_off, edge_cnt, x, W1, b1, W2, b2,
                                                   band_e, band_v, st, band_key);

    bhist1_kernel<<<64, 256, 0, stream>>>(band_key, st, hist);
    bscan_kernel<<<1, 256, 0, stream>>>(hist, st, 0);
    bhist2_kernel<<<64, 256, 0, stream>>>(band_key, st, hist);
    bscan_kernel<<<1, 256, 0, stream>>>(hist, st, 1);
    btie_kernel<<<BANDCAP / 256, 256, 0, stream>>>(band_key, band_j, band_p, st, flag,
                                                   tie_k, tie_j, tie_p);
    btierank_kernel<<<1, 256, 0, stream>>>(tie_k, tie_j, tie_p, st, flag);

    out_kernel<<<(NNZ + 255) / 256, 256, 0, stream>>>(probs_b, flag, pos, st, o_probs, o_soft, o_hard);
    edge_out_kernel<<<(N_EDGES + 255) / 256, 256, 0, stream>>>(probs_b, flag, edge_off, edge_cnt, st,
                                                               o_es, o_eh);
}

// Round 13
// 853.184 us; speedup vs baseline: 1.4929x; 1.4929x over previous
//
#include <hip/hip_runtime.h>
#include <math.h>

#define N_NODES   100000
#define N_EDGES   200000
#define NNZ       2000000
#define K_KEEP    1000000
#define BANDCAP   131072
#define TIECAP    4096
#define DELTA     1.0e-3f
#define SCAN_BLOCKS 196   // ceil(200000/1024)
#define USCALE (4294967296.0 / 4.0e-3)   // band key -> u32 map; band width < 4e-3 guaranteed

// ---------------- workspace layout (bytes) ----------------
#define OFF_PAB   ((size_t)0)          // float2 p_ab2 [N_NODES*32] 25,600,000 (.x=a_vk, .y=b_vk)
#define OFF_PB32  ((size_t)25600000)   // f32 probs_b [NNZ]        8,000,000 (CSR/p-order probs)
#define OFF_VJ    ((size_t)33600000)   // uint2 vj [NNZ]          16,000,000 (.x=vertex, .y=orig j)
#define OFF_POS   ((size_t)49600000)   // u32 pos [NNZ] j->p       8,000,000
#define OFF_EOFF  ((size_t)57600000)   // u32 edge_off [N_EDGES]     800,000
#define OFF_CUR   ((size_t)58400000)   // u32 cursor [N_EDGES]       800,000
#define OFF_BS    ((size_t)59200000)   // u32 bsums [256]              1,024
#define OFF_BANDP ((size_t)59201024)   // u32 band_p [BANDCAP]       524,288
#define OFF_BANDJ ((size_t)59725312)   // u32 band_j [BANDCAP]       524,288
#define OFF_BANDE ((size_t)60249600)   // u32 band_e [BANDCAP]       524,288
#define OFF_BANDV ((size_t)60773888)   // u32 band_v [BANDCAP]       524,288
#define OFF_BANDK ((size_t)61298176)   // u64 band_key [BANDCAP]   1,048,576
#define OFF_TIEK  ((size_t)62346752)   // u64 tie_k [TIECAP]          32,768
#define OFF_TIEJ  ((size_t)62379520)   // u32 tie_j [TIECAP]          16,384
#define OFF_TIEP  ((size_t)62395904)   // u32 tie_p [TIECAP]          16,384
// --- zero region ---
#define OFF_FLAG  ((size_t)62412288)   // u8  flag [NNZ]           2,000,000 (0 none, 2 selected)
#define OFF_ECNT  ((size_t)64412288)   // u32 edge_cnt [N_EDGES]     800,000
#define OFF_HIST  ((size_t)65212288)   // u32 hist [4*2048]           32,768
#define OFF_ST    ((size_t)65245056)   // SelState                        64
#define ZERO_OFF  OFF_FLAG
#define ZERO_LEN  ((size_t)(65245120 - 62412288))

struct SelState {
    unsigned int B1;        // f32 pass-1 bucket
    unsigned int rem1;      // remaining rank within B1
    float lo_edge, hi_edge; // band boundaries
    unsigned int n_hi;      // count of f32 probs > hi_edge
    unsigned int band_n;    // band append counter
    unsigned int bB1;       // band-select pass-1 bucket (u32 map, bits 31:21)
    unsigned int brem1;     // remaining rank within bB1
    unsigned int bU0;       // threshold u-bucket base (width 1024)
    unsigned int brem2;     // remaining rank within the u-bucket
    unsigned int tie_n;     // tie-bucket append counter
};

__device__ __forceinline__ unsigned int band_u32(double key, float lo) {
    double t = (key - (double)lo) * USCALE;
    t = t < 0.0 ? 0.0 : (t > 4294967295.0 ? 4294967295.0 : t);
    return (unsigned int)t;   // monotone non-decreasing in key
}

// p_ab2[v][k] = (sum_d x[v][d]*W1[d][k], sum_d x[v][d]*W1[64+d][k])
__global__ void proj_kernel(const float* __restrict__ x, const float* __restrict__ W1,
                            float2* __restrict__ p_ab2) {
    __shared__ float sW[128 * 32];
    __shared__ float sx[8][64];
    for (int t = threadIdx.x; t < 128 * 32; t += 256) sW[t] = W1[t];
    int base = blockIdx.x * 8;
    for (int t = threadIdx.x; t < 512; t += 256) {
        int n = t >> 6, d = t & 63;
        int g = base + n;
        sx[n][d] = (g < N_NODES) ? x[(size_t)g * 64 + d] : 0.f;
    }
    __syncthreads();
    int ln = threadIdx.x >> 5;
    int k  = threadIdx.x & 31;
    int node = base + ln;
    if (node >= N_NODES) return;
    float sa = 0.f, sb = 0.f;
    for (int d = 0; d < 64; ++d) {
        float xv = sx[ln][d];
        sa += xv * sW[d * 32 + k];
        sb += xv * sW[(64 + d) * 32 + k];
    }
    p_ab2[(size_t)node * 32 + k] = make_float2(sa, sb);
}

// ---------------- CSR build ----------------
__global__ void count_kernel(const int* __restrict__ E, unsigned int* __restrict__ edge_cnt) {
    int j = blockIdx.x * 256 + threadIdx.x;
    if (j >= NNZ) return;
    atomicAdd(&edge_cnt[E[j]], 1u);
}

__global__ void scanA_kernel(const unsigned int* __restrict__ edge_cnt,
                             unsigned int* __restrict__ edge_off, unsigned int* __restrict__ bsums) {
    __shared__ unsigned int s[256];
    int tid = threadIdx.x;
    int base = blockIdx.x * 1024 + tid * 4;
    unsigned int v0 = (base + 0 < N_EDGES) ? edge_cnt[base + 0] : 0u;
    unsigned int v1 = (base + 1 < N_EDGES) ? edge_cnt[base + 1] : 0u;
    unsigned int v2 = (base + 2 < N_EDGES) ? edge_cnt[base + 2] : 0u;
    unsigned int v3 = (base + 3 < N_EDGES) ? edge_cnt[base + 3] : 0u;
    unsigned int tsum = v0 + v1 + v2 + v3;
    s[tid] = tsum;
    __syncthreads();
    for (int off = 1; off < 256; off <<= 1) {
        unsigned int t = (tid >= off) ? s[tid - off] : 0u;
        __syncthreads();
        s[tid] += t;
        __syncthreads();
    }
    unsigned int excl = s[tid] - tsum;
    if (base + 0 < N_EDGES) edge_off[base + 0] = excl;
    if (base + 1 < N_EDGES) edge_off[base + 1] = excl + v0;
    if (base + 2 < N_EDGES) edge_off[base + 2] = excl + v0 + v1;
    if (base + 3 < N_EDGES) edge_off[base + 3] = excl + v0 + v1 + v2;
    if (tid == 255) bsums[blockIdx.x] = s[255];
}

__global__ void scanB_kernel(unsigned int* __restrict__ bsums) {
    __shared__ unsigned int s[256];
    int tid = threadIdx.x;
    unsigned int v = (tid < SCAN_BLOCKS) ? bsums[tid] : 0u;
    s[tid] = v;
    __syncthreads();
    for (int off = 1; off < 256; off <<= 1) {
        unsigned int t = (tid >= off) ? s[tid - off] : 0u;
        __syncthreads();
        s[tid] += t;
        __syncthreads();
    }
    if (tid < SCAN_BLOCKS) bsums[tid] = s[tid] - v;
}

__global__ void scanC_kernel(unsigned int* __restrict__ edge_off, const unsigned int* __restrict__ bsums,
                             unsigned int* __restrict__ cursor) {
    int i = blockIdx.x * 256 + threadIdx.x;
    if (i >= N_EDGES) return;
    unsigned int o = edge_off[i] + bsums[i >> 10];
    edge_off[i] = o;
    cursor[i] = o;
}

// 8 incidences/thread: 8 independent atomic returns in flight (hide far-atomic latency)
__global__ void bucket_kernel(const int* __restrict__ V, const int* __restrict__ E,
                              unsigned int* __restrict__ cursor,
                              uint2* __restrict__ vj, unsigned int* __restrict__ pos) {
    unsigned int base = blockIdx.x * 2048 + threadIdx.x;
    int ev[8], vv[8];
    unsigned int pp[8];
    #pragma unroll
    for (int c = 0; c < 8; ++c) {
        unsigned int j = base + 256u * c;
        if (j < NNZ) { ev[c] = E[j]; vv[c] = V[j]; }
    }
    #pragma unroll
    for (int c = 0; c < 8; ++c) {
        unsigned int j = base + 256u * c;
        if (j < NNZ) pp[c] = atomicAdd(&cursor[ev[c]], 1u);
    }
    #pragma unroll
    for (int c = 0; c < 8; ++c) {
        unsigned int j = base + 256u * c;
        if (j < NNZ) {
            vj[pp[c]] = make_uint2((unsigned int)vv[c], j);
            pos[j] = pp[c];
        }
    }
}

// ---------------- fused per-edge mean + per-incidence MLP (f32, CSR-order writes) ----------------
__global__ void edge_logit_kernel(const uint2* __restrict__ vj,
                                  const unsigned int* __restrict__ edge_off,
                                  const unsigned int* __restrict__ edge_cnt,
                                  const float2* __restrict__ p_ab2,
                                  const float* __restrict__ b1, const float* __restrict__ W2,
                                  const float* __restrict__ b2,
                                  float* __restrict__ probs_b, float* __restrict__ o_ep) {
    __shared__ float sa[4][32 * 32];   // 16 KB: [wave][slot i][k]
    __shared__ float slog[4][32];      // per-incidence logits
    int e = blockIdx.x * 4 + (threadIdx.x >> 6);
    if (e >= N_EDGES) return;
    int w    = threadIdx.x >> 6;
    int lane = threadIdx.x & 63;
    int k    = lane & 31;
    unsigned int half = (unsigned int)(lane >> 5);

    unsigned int off = edge_off[e];
    unsigned int deg = edge_cnt[e];
    unsigned int mind = deg < 32u ? deg : 32u;

    // coalesced member-id preload (lanes 0..mind-1)
    unsigned int myv = ((unsigned int)lane < mind) ? vj[off + lane].x : 0u;

    float bacc = 0.f;
    for (unsigned int i = half; i < mind; i += 2u) {
        unsigned int v = (unsigned int)__shfl((int)myv, (int)i, 64);
        float2 r = p_ab2[(size_t)v * 32u + k];
        sa[w][i * 32 + k] = r.x;
        bacc += r.y;
    }
    for (unsigned int i = 32u + half; i < deg; i += 2u) {   // deg>32 tail: b only
        unsigned int v = vj[off + i].x;
        bacc += p_ab2[(size_t)v * 32u + k].y;
    }

    float cc  = (float)(deg > 1u ? deg : 1u);
    float emk = (bacc + __shfl_xor(bacc, 32)) / cc + b1[k];
    float w2k = W2[k];
    float b2v = b2[0];
    float prsum = 0.f;

    for (unsigned int i = half; i < mind; i += 2u) {
        float hk = sa[w][i * 32 + k] + emk;
        hk = hk > 0.f ? hk : 0.f;
        float t = hk * w2k;
        #pragma unroll
        for (int o = 16; o > 0; o >>= 1) t += __shfl_down(t, o, 32);
        if (k == 0) slog[w][i] = t;
    }
    // vectorized epilogue: lane i <-> incidence i (same wave; LDS ops in order)
    if ((unsigned int)lane < mind) {
        float pr = 1.f / (1.f + __expf(-(slog[w][lane] + b2v)));
        probs_b[off + lane] = pr;      // coalesced
        prsum = pr;
    }
    for (unsigned int i = 32u + half; i < deg; i += 2u) {   // deg>32 tail: a from global
        unsigned int v = vj[off + i].x;
        float hk = p_ab2[(size_t)v * 32u + k].x + emk;
        hk = hk > 0.f ? hk : 0.f;
        float t = hk * w2k;
        #pragma unroll
        for (int o = 16; o > 0; o >>= 1) t += __shfl_down(t, o, 32);
        if (k == 0) {
            float pr = 1.f / (1.f + __expf(-(t + b2v)));
            probs_b[off + i] = pr;
            prsum += pr;
        }
    }
    #pragma unroll
    for (int o = 32; o > 0; o >>= 1) prsum += __shfl_down(prsum, o, 64);
    if (lane == 0) o_ep[e] = prsum / cc;
}

// ---------------- 2-level radix histogram on f32 keys ----------------
__global__ void hist1_kernel(const float* __restrict__ probs_b, unsigned int* __restrict__ hist) {
    __shared__ unsigned int lh[2048];
    for (int t = threadIdx.x; t < 2048; t += 256) lh[t] = 0;
    __syncthreads();
    for (unsigned int i = blockIdx.x * 256 + threadIdx.x; i < NNZ; i += gridDim.x * 256) {
        unsigned int key = __float_as_uint(probs_b[i]);
        atomicAdd(&lh[key >> 21], 1u);
    }
    __syncthreads();
    for (int t = threadIdx.x; t < 2048; t += 256)
        if (lh[t]) atomicAdd(&hist[t], lh[t]);
}

__global__ void hist2_kernel(const float* __restrict__ probs_b, const SelState* __restrict__ st,
                             unsigned int* __restrict__ hist) {
    __shared__ unsigned int lh[2048];
    for (int t = threadIdx.x; t < 2048; t += 256) lh[t] = 0;
    __syncthreads();
    unsigned int B1 = st->B1;
    for (unsigned int i = blockIdx.x * 256 + threadIdx.x; i < NNZ; i += gridDim.x * 256) {
        unsigned int key = __float_as_uint(probs_b[i]);
        if ((key >> 21) == B1) atomicAdd(&lh[(key >> 10) & 2047u], 1u);
    }
    __syncthreads();
    for (int t = threadIdx.x; t < 2048; t += 256)
        if (lh[t]) atomicAdd(&hist[2048 + t], lh[t]);
}

// which=0: select bucket B1 at rank K_KEEP; which=1: select B2 at rank rem1, set band edges
__global__ void scan_sel_kernel(const unsigned int* __restrict__ hist, SelState* __restrict__ st, int which) {
    __shared__ unsigned int csum[256];
    int t = threadIdx.x;
    unsigned int target = (which == 0) ? (unsigned int)K_KEEP : st->rem1;
    const unsigned int* h = hist + (which ? 2048 : 0);
    unsigned int b[8];
    unsigned int s = 0;
    #pragma unroll
    for (int i = 0; i < 8; ++i) { b[i] = h[t * 8 + i]; s += b[i]; }
    csum[t] = s;
    __syncthreads();
    for (int off = 1; off < 256; off <<= 1) {
        unsigned int v = (t + off < 256) ? csum[t + off] : 0u;
        __syncthreads();
        csum[t] += v;
        __syncthreads();
    }
    unsigned int above = csum[t] - s;       // sum over chunks > t
    if (above < target && target <= above + s) {
        unsigned int rem = target - above;
        unsigned int cum = 0;
        #pragma unroll
        for (int i = 7; i >= 0; --i) {
            if (rem <= cum + b[i]) {
                unsigned int bin = (unsigned int)(t * 8 + i);
                if (which == 0) { st->B1 = bin; st->rem1 = rem - cum; }
                else {
                    unsigned int P = (st->B1 << 21) | (bin << 10);
                    st->lo_edge = __uint_as_float(P) - DELTA;
                    st->hi_edge = __uint_as_float(P + 1024u) + DELTA;
                }
                break;
            }
            cum += b[i];
        }
    }
}

// fused: count n_hi + LDS-aggregated band append, single coalesced probs pass
__global__ void bandsel_kernel(const float* __restrict__ probs_b, const int* __restrict__ E,
                               const uint2* __restrict__ vj,
                               SelState* __restrict__ st,
                               unsigned int* __restrict__ band_p, unsigned int* __restrict__ band_j,
                               unsigned int* __restrict__ band_e, unsigned int* __restrict__ band_v) {
    __shared__ unsigned int scnt, sbase, hicnt;
    if (threadIdx.x == 0) { scnt = 0; hicnt = 0; }
    __syncthreads();
    unsigned int p = blockIdx.x * 256 + threadIdx.x;
    float hi = st->hi_edge, lo = st->lo_edge;
    bool valid = p < NNZ;
    float pk = valid ? probs_b[p] : -1.f;
    bool ishi = pk > hi;
    bool isband = valid && !ishi && pk >= lo;
    unsigned long long m = __ballot(ishi);
    if ((threadIdx.x & 63) == 0 && m) atomicAdd(&hicnt, (unsigned int)__popcll(m));
    unsigned int local = 0;
    if (isband) local = atomicAdd(&scnt, 1u);     // LDS atomic: on-CU, fast
    __syncthreads();
    if (threadIdx.x == 0) {
        if (scnt) sbase = atomicAdd(&st->band_n, scnt);
        if (hicnt) atomicAdd(&st->n_hi, hicnt);
    }
    __syncthreads();
    if (isband) {
        unsigned int s = sbase + local;
        if (s < BANDCAP) {
            uint2 t = vj[p];
            band_p[s] = p;
            band_j[s] = t.y;
            band_e[s] = (unsigned int)E[t.y];
            band_v[s] = t.x;
        }
    }
}

// exact f64 recompute for band members; W1 staged in LDS
__global__ void rescue_kernel(const uint2* __restrict__ vj,
                              const unsigned int* __restrict__ edge_off,
                              const unsigned int* __restrict__ edge_cnt,
                              const float* __restrict__ x, const float* __restrict__ W1,
                              const float* __restrict__ b1, const float* __restrict__ W2,
                              const float* __restrict__ b2,
                              const unsigned int* __restrict__ band_e,
                              const unsigned int* __restrict__ band_v,
                              const SelState* __restrict__ st,
                              unsigned long long* __restrict__ band_key) {
    unsigned int n = st->band_n; if (n > BANDCAP) n = BANDCAP;
    if (blockIdx.x * 8 >= n) return;
    __shared__ float sW[128 * 32];
    for (int t = threadIdx.x; t < 128 * 32; t += 256) sW[t] = W1[t];
    __syncthreads();
    unsigned int g = blockIdx.x * 8 + (threadIdx.x >> 5);
    if (g >= n) return;
    int k = threadIdx.x & 31;
    unsigned int v = band_v[g];
    unsigned int e = band_e[g];
    unsigned int off = edge_off[e];
    unsigned int deg = edge_cnt[e];

    const float* xv = x + (size_t)v * 64u;
    double a = 0.0;
    #pragma unroll 8
    for (int d = 0; d < 64; ++d) a += (double)xv[d] * (double)sW[d * 32 + k];
    double bsum = 0.0;
    for (unsigned int m = off; m < off + deg; ++m) {
        const float* xm = x + (size_t)vj[m].x * 64u;
        double acc = 0.0;
        #pragma unroll 8
        for (int d = 0; d < 64; ++d) acc += (double)xm[d] * (double)sW[(64 + d) * 32 + k];
        bsum += acc;
    }
    double cc = (double)(deg > 1u ? deg : 1u);
    double h = a + bsum / cc + (double)b1[k];
    h = h > 0.0 ? h : 0.0;
    double t = h * (double)W2[k];
    #pragma unroll
    for (int o = 16; o > 0; o >>= 1) t += __shfl_down(t, o, 32);
    if (k == 0) {
        double pr = 1.0 / (1.0 + exp(-(t + (double)b2[0])));
        band_key[g] = (unsigned long long)__double_as_longlong(pr);
    }
}

// ---------------- O(n) band selection: 2-level hist on monotone u32 map ----------------
__global__ void bhist1_kernel(const unsigned long long* __restrict__ band_key,
                              const SelState* __restrict__ st, unsigned int* __restrict__ hist) {
    __shared__ unsigned int lh[2048];
    for (int t = threadIdx.x; t < 2048; t += 256) lh[t] = 0;
    __syncthreads();
    unsigned int n = st->band_n; if (n > BANDCAP) n = BANDCAP;
    float lo = st->lo_edge;
    for (unsigned int i = blockIdx.x * 256 + threadIdx.x; i < n; i += gridDim.x * 256) {
        unsigned int u = band_u32(__longlong_as_double((long long)band_key[i]), lo);
        atomicAdd(&lh[u >> 21], 1u);
    }
    __syncthreads();
    for (int t = threadIdx.x; t < 2048; t += 256)
        if (lh[t]) atomicAdd(&hist[4096 + t], lh[t]);
}

__global__ void bhist2_kernel(const unsigned long long* __restrict__ band_key,
                              const SelState* __restrict__ st, unsigned int* __restrict__ hist) {
    __shared__ unsigned int lh[2048];
    for (int t = threadIdx.x; t < 2048; t += 256) lh[t] = 0;
    __syncthreads();
    unsigned int n = st->band_n; if (n > BANDCAP) n = BANDCAP;
    float lo = st->lo_edge;
    unsigned int bB1 = st->bB1;
    for (unsigned int i = blockIdx.x * 256 + threadIdx.x; i < n; i += gridDim.x * 256) {
        unsigned int u = band_u32(__longlong_as_double((long long)band_key[i]), lo);
        if ((u >> 21) == bB1) atomicAdd(&lh[(u >> 10) & 2047u], 1u);
    }
    __syncthreads();
    for (int t = threadIdx.x; t < 2048; t += 256)
        if (lh[t]) atomicAdd(&hist[6144 + t], lh[t]);
}

// which=0: bucket bB1 at rank (K_KEEP - n_hi); which=1: bucket bB2 at rank brem1 -> bU0, brem2
__global__ void bscan_kernel(const unsigned int* __restrict__ hist, SelState* __restrict__ st, int which) {
    __shared__ unsigned int csum[256];
    int t = threadIdx.x;
    unsigned int target = (which == 0) ? ((unsigned int)K_KEEP - st->n_hi) : st->brem1;
    const unsigned int* h = hist + (which ? 6144 : 4096);
    unsigned int b[8];
    unsigned int s = 0;
    #pragma unroll
    for (int i = 0; i < 8; ++i) { b[i] = h[t * 8 + i]; s += b[i]; }
    csum[t] = s;
    __syncthreads();
    for (int off = 1; off < 256; off <<= 1) {
        unsigned int v = (t + off < 256) ? csum[t + off] : 0u;
        __syncthreads();
        csum[t] += v;
        __syncthreads();
    }
    unsigned int above = csum[t] - s;
    if (above < target && target <= above + s) {
        unsigned int rem = target - above;
        unsigned int cum = 0;
        #pragma unroll
        for (int i = 7; i >= 0; --i) {
            if (rem <= cum + b[i]) {
                unsigned int bin = (unsigned int)(t * 8 + i);
                if (which == 0) { st->bB1 = bin; st->brem1 = rem - cum; }
                else            { st->bU0 = (st->bB1 << 21) | (bin << 10); st->brem2 = rem - cum; }
                break;
            }
            cum += b[i];
        }
    }
}

// mark u >= bU0+1024 selected; collect tie bucket [bU0, bU0+1024)
__global__ void btie_kernel(const unsigned long long* __restrict__ band_key,
                            const unsigned int* __restrict__ band_j,
                            const unsigned int* __restrict__ band_p,
                            SelState* __restrict__ st, unsigned char* __restrict__ flag,
                            unsigned long long* __restrict__ tie_k,
                            unsigned int* __restrict__ tie_j, unsigned int* __restrict__ tie_p) {
    unsigned int n = st->band_n; if (n > BANDCAP) n = BANDCAP;
    unsigned int i = blockIdx.x * 256 + threadIdx.x;
    if (i >= n) return;
    float lo = st->lo_edge;
    unsigned int U0 = st->bU0;
    unsigned long long key = band_key[i];
    unsigned int u = band_u32(__longlong_as_double((long long)key), lo);
    if (u >= U0 + 1024u) {
        flag[band_p[i]] = 2u;
    } else if (u >= U0) {
        unsigned int s = atomicAdd(&st->tie_n, 1u);
        if (s < TIECAP) { tie_k[s] = key; tie_j[s] = band_j[i]; tie_p[s] = band_p[i]; }
    }
}

// exact rank inside the (tiny) tie bucket by (key desc, j asc); take first brem2
__global__ void btierank_kernel(const unsigned long long* __restrict__ tie_k,
                                const unsigned int* __restrict__ tie_j,
                                const unsigned int* __restrict__ tie_p,
                                const SelState* __restrict__ st, unsigned char* __restrict__ flag) {
    unsigned int n = st->tie_n; if (n > TIECAP) n = TIECAP;
    unsigned int need = st->brem2;
    for (unsigned int i = threadIdx.x; i < n; i += 256) {
        unsigned long long ki = tie_k[i];
        unsigned int ji = tie_j[i];
        unsigned int r = 0;
        for (unsigned int q = 0; q < n; ++q) {
            unsigned long long kq = tie_k[q];
            if (kq > ki || (kq == ki && tie_j[q] < ji)) r++;
        }
        if (r < need) flag[tie_p[i]] = 2u;
    }
}

// j-order coalesced outputs; hard bit computed inline from gathered probs/flag
__global__ void out_kernel(const float* __restrict__ probs_b, const unsigned char* __restrict__ flag,
                           const unsigned int* __restrict__ pos, const SelState* __restrict__ st,
                           float* __restrict__ o_probs, float* __restrict__ o_soft, float* __restrict__ o_hard) {
    unsigned int j = blockIdx.x * 256 + threadIdx.x;
    if (j >= NNZ) return;
    float hi = st->hi_edge;
    unsigned int p = pos[j];
    float pk = probs_b[p];
    float hb = (pk > hi || flag[p] == 2u) ? 1.f : 0.f;
    o_probs[j] = pk;
    o_soft[j]  = hb;
    o_hard[j]  = hb;
}

// per-edge: edge_soft / edge_hard recomputed from CSR-coalesced probs/flag
__global__ void edge_out_kernel(const float* __restrict__ probs_b, const unsigned char* __restrict__ flag,
                                const unsigned int* __restrict__ edge_off,
                                const unsigned int* __restrict__ edge_cnt,
                                const SelState* __restrict__ st,
                                float* __restrict__ o_es, float* __restrict__ o_eh) {
    unsigned int e = blockIdx.x * 256 + threadIdx.x;
    if (e >= N_EDGES) return;
    float hi = st->hi_edge;
    unsigned int off = edge_off[e], deg = edge_cnt[e];
    unsigned int cnt = 0;
    for (unsigned int i = 0; i < deg; ++i)
        cnt += (probs_b[off + i] > hi || flag[off + i] == 2u) ? 1u : 0u;
    float cc = (float)(deg > 1u ? deg : 1u);
    o_es[e] = (float)cnt / cc;
    o_eh[e] = cnt ? 1.f : 0.f;
}

extern "C" void kernel_launch(void* const* d_in, const int* in_sizes, int n_in,
                              void* d_out, int out_size, void* d_ws, size_t ws_size,
                              hipStream_t stream) {
    const float* x  = (const float*)d_in[0];
    const int*   V  = (const int*)d_in[1];
    const int*   E  = (const int*)d_in[2];
    const float* W1 = (const float*)d_in[3];
    const float* b1 = (const float*)d_in[4];
    const float* W2 = (const float*)d_in[5];
    const float* b2 = (const float*)d_in[6];

    float* out     = (float*)d_out;
    float* o_probs = out;
    float* o_soft  = out + NNZ;
    float* o_hard  = out + 2 * (size_t)NNZ;
    float* o_ep    = out + 3 * (size_t)NNZ;
    float* o_es    = out + 3 * (size_t)NNZ + N_EDGES;
    float* o_eh    = out + 3 * (size_t)NNZ + 2 * (size_t)N_EDGES;

    char* w = (char*)d_ws;
    float2*             p_ab2    = (float2*)(w + OFF_PAB);
    float*              probs_b  = (float*)(w + OFF_PB32);
    uint2*              vj       = (uint2*)(w + OFF_VJ);
    unsigned int*       pos      = (unsigned int*)(w + OFF_POS);
    unsigned int*       edge_off = (unsigned int*)(w + OFF_EOFF);
    unsigned int*       cursor   = (unsigned int*)(w + OFF_CUR);
    unsigned int*       bsums    = (unsigned int*)(w + OFF_BS);
    unsigned int*       band_p   = (unsigned int*)(w + OFF_BANDP);
    unsigned int*       band_j   = (unsigned int*)(w + OFF_BANDJ);
    unsigned int*       band_e   = (unsigned int*)(w + OFF_BANDE);
    unsigned int*       band_v   = (unsigned int*)(w + OFF_BANDV);
    unsigned long long* band_key = (unsigned long long*)(w + OFF_BANDK);
    unsigned long long* tie_k    = (unsigned long long*)(w + OFF_TIEK);
    unsigned int*       tie_j    = (unsigned int*)(w + OFF_TIEJ);
    unsigned int*       tie_p    = (unsigned int*)(w + OFF_TIEP);
    unsigned char*      flag     = (unsigned char*)(w + OFF_FLAG);
    unsigned int*       edge_cnt = (unsigned int*)(w + OFF_ECNT);
    unsigned int*       hist     = (unsigned int*)(w + OFF_HIST);
    SelState*           st       = (SelState*)(w + OFF_ST);

    hipMemsetAsync(w + ZERO_OFF, 0, ZERO_LEN, stream);

    proj_kernel<<<(N_NODES + 7) / 8, 256, 0, stream>>>(x, W1, p_ab2);

    count_kernel<<<(NNZ + 255) / 256, 256, 0, stream>>>(E, edge_cnt);
    scanA_kernel<<<SCAN_BLOCKS, 256, 0, stream>>>(edge_cnt, edge_off, bsums);
    scanB_kernel<<<1, 256, 0, stream>>>(bsums);
    scanC_kernel<<<(N_EDGES + 255) / 256, 256, 0, stream>>>(edge_off, bsums, cursor);
    bucket_kernel<<<(NNZ + 2047) / 2048, 256, 0, stream>>>(V, E, cursor, vj, pos);

    edge_logit_kernel<<<(N_EDGES + 3) / 4, 256, 0, stream>>>(vj, edge_off, edge_cnt,
                                                             p_ab2, b1, W2, b2, probs_b, o_ep);

    hist1_kernel<<<1024, 256, 0, stream>>>(probs_b, hist);
    scan_sel_kernel<<<1, 256, 0, stream>>>(hist, st, 0);
    hist2_kernel<<<1024, 256, 0, stream>>>(probs_b, st, hist);
    scan_sel_kernel<<<1, 256, 0, stream>>>(hist, st, 1);

    bandsel_kernel<<<(NNZ + 255) / 256, 256, 0, stream>>>(probs_b, E, vj, st,
                                                          band_p, band_j, band_e, band_v);
    rescue_kernel<<<BANDCAP / 8, 256, 0, stream>>>(vj, edge_off, edge_cnt, x, W1, b1, W2, b2,
                                                   band_e, band_v, st, band_key);

    bhist1_kernel<<<64, 256, 0, stream>>>(band_key, st, hist);
    bscan_kernel<<<1, 256, 0, stream>>>(hist, st, 0);
    bhist2_kernel<<<64, 256, 0, stream>>>(band_key, st, hist);
    bscan_kernel<<<1, 256, 0, stream>>>(hist, st, 1);
    btie_kernel<<<BANDCAP / 256, 256, 0, stream>>>(band_key, band_j, band_p, st, flag,
                                                   tie_k, tie_j, tie_p);
    btierank_kernel<<<1, 256, 0, stream>>>(tie_k, tie_j, tie_p, st, flag);

    out_kernel<<<(NNZ + 255) / 256, 256, 0, stream>>>(probs_b, flag, pos, st, o_probs, o_soft, o_hard);
    edge_out_kernel<<<(N_EDGES + 255) / 256, 256, 0, stream>>>(probs_b, flag, edge_off, edge_cnt, st,
                                                               o_es, o_eh);
}

// Round 14
// 704.559 us; speedup vs baseline: 1.8078x; 1.2109x over previous
//
#include <hip/hip_runtime.h>
#include <math.h>

#define N_NODES   100000
#define N_EDGES   200000
#define NNZ       2000000
#define K_KEEP    1000000
#define BANDCAP   131072
#define TIECAP    4096
#define DELTA     1.0e-3f
#define SCAN_BLOCKS 196   // ceil(200000/1024)
#define USCALE (4294967296.0 / 4.0e-3)   // band key -> u32 map; band width < 4e-3 guaranteed

// ---------------- workspace layout (bytes) ----------------
#define OFF_PAB   ((size_t)0)          // float2 p_ab2 [N_NODES*32] 25,600,000 (.x=a_vk, .y=b_vk)
#define OFF_PB32  ((size_t)25600000)   // f32 probs_b [NNZ]        8,000,000 (CSR/p-order probs)
#define OFF_VJ    ((size_t)33600000)   // uint2 vj [NNZ]          16,000,000 (.x=vertex, .y=orig j)
#define OFF_POS   ((size_t)49600000)   // u32 pos [NNZ] j->p       8,000,000
#define OFF_EOFF  ((size_t)57600000)   // u32 edge_off [N_EDGES]     800,000
#define OFF_CUR   ((size_t)58400000)   // u32 cursor [N_EDGES]       800,000
#define OFF_BS    ((size_t)59200000)   // u32 bsums [256]              1,024
#define OFF_BANDP ((size_t)59201024)   // u32 band_p [BANDCAP]       524,288
#define OFF_BANDJ ((size_t)59725312)   // u32 band_j [BANDCAP]       524,288
#define OFF_BANDE ((size_t)60249600)   // u32 band_e [BANDCAP]       524,288
#define OFF_BANDV ((size_t)60773888)   // u32 band_v [BANDCAP]       524,288
#define OFF_BANDK ((size_t)61298176)   // u64 band_key [BANDCAP]   1,048,576
#define OFF_TIEK  ((size_t)62346752)   // u64 tie_k [TIECAP]          32,768
#define OFF_TIEJ  ((size_t)62379520)   // u32 tie_j [TIECAP]          16,384
#define OFF_TIEP  ((size_t)62395904)   // u32 tie_p [TIECAP]          16,384
// --- zero region ---
#define OFF_FLAG  ((size_t)62412288)   // u8  flag [NNZ]           2,000,000 (0 none, 2 selected)
#define OFF_ECNT  ((size_t)64412288)   // u32 edge_cnt [N_EDGES]     800,000
#define OFF_HIST  ((size_t)65212288)   // u32 hist [4*2048]           32,768
#define OFF_ST    ((size_t)65245056)   // SelState (padded)              256
#define ZERO_OFF  OFF_FLAG
#define ZERO_LEN  ((size_t)(65245312 - 62412288))

// hot atomic counters (n_hi, band_n, tie_n) each on their own 64B line
struct SelState {
    unsigned int B1;        // f32 pass-1 bucket
    unsigned int rem1;      // remaining rank within B1
    float lo_edge, hi_edge; // band boundaries
    unsigned int bB1;       // band-select pass-1 bucket (u32 map, bits 31:21)
    unsigned int brem1;     // remaining rank within bB1
    unsigned int bU0;       // threshold u-bucket base (width 1024)
    unsigned int brem2;     // remaining rank within the u-bucket
    unsigned int _pad0[8];  // -> 64 B
    unsigned int n_hi;      unsigned int _pad1[15];   // own line
    unsigned int band_n;    unsigned int _pad2[15];   // own line
    unsigned int tie_n;     unsigned int _pad3[15];   // own line
};

__device__ __forceinline__ unsigned int band_u32(double key, float lo) {
    double t = (key - (double)lo) * USCALE;
    t = t < 0.0 ? 0.0 : (t > 4294967295.0 ? 4294967295.0 : t);
    return (unsigned int)t;   // monotone non-decreasing in key
}

// p_ab2[v][k] = (sum_d x[v][d]*W1[d][k], sum_d x[v][d]*W1[64+d][k])
__global__ void proj_kernel(const float* __restrict__ x, const float* __restrict__ W1,
                            float2* __restrict__ p_ab2) {
    __shared__ float sW[128 * 32];
    __shared__ float sx[8][64];
    for (int t = threadIdx.x; t < 128 * 32; t += 256) sW[t] = W1[t];
    int base = blockIdx.x * 8;
    for (int t = threadIdx.x; t < 512; t += 256) {
        int n = t >> 6, d = t & 63;
        int g = base + n;
        sx[n][d] = (g < N_NODES) ? x[(size_t)g * 64 + d] : 0.f;
    }
    __syncthreads();
    int ln = threadIdx.x >> 5;
    int k  = threadIdx.x & 31;
    int node = base + ln;
    if (node >= N_NODES) return;
    float sa = 0.f, sb = 0.f;
    for (int d = 0; d < 64; ++d) {
        float xv = sx[ln][d];
        sa += xv * sW[d * 32 + k];
        sb += xv * sW[(64 + d) * 32 + k];
    }
    p_ab2[(size_t)node * 32 + k] = make_float2(sa, sb);
}

// ---------------- CSR build ----------------
__global__ void count_kernel(const int* __restrict__ E, unsigned int* __restrict__ edge_cnt) {
    int j = blockIdx.x * 256 + threadIdx.x;
    if (j >= NNZ) return;
    atomicAdd(&edge_cnt[E[j]], 1u);
}

__global__ void scanA_kernel(const unsigned int* __restrict__ edge_cnt,
                             unsigned int* __restrict__ edge_off, unsigned int* __restrict__ bsums) {
    __shared__ unsigned int s[256];
    int tid = threadIdx.x;
    int base = blockIdx.x * 1024 + tid * 4;
    unsigned int v0 = (base + 0 < N_EDGES) ? edge_cnt[base + 0] : 0u;
    unsigned int v1 = (base + 1 < N_EDGES) ? edge_cnt[base + 1] : 0u;
    unsigned int v2 = (base + 2 < N_EDGES) ? edge_cnt[base + 2] : 0u;
    unsigned int v3 = (base + 3 < N_EDGES) ? edge_cnt[base + 3] : 0u;
    unsigned int tsum = v0 + v1 + v2 + v3;
    s[tid] = tsum;
    __syncthreads();
    for (int off = 1; off < 256; off <<= 1) {
        unsigned int t = (tid >= off) ? s[tid - off] : 0u;
        __syncthreads();
        s[tid] += t;
        __syncthreads();
    }
    unsigned int excl = s[tid] - tsum;
    if (base + 0 < N_EDGES) edge_off[base + 0] = excl;
    if (base + 1 < N_EDGES) edge_off[base + 1] = excl + v0;
    if (base + 2 < N_EDGES) edge_off[base + 2] = excl + v0 + v1;
    if (base + 3 < N_EDGES) edge_off[base + 3] = excl + v0 + v1 + v2;
    if (tid == 255) bsums[blockIdx.x] = s[255];
}

__global__ void scanB_kernel(unsigned int* __restrict__ bsums) {
    __shared__ unsigned int s[256];
    int tid = threadIdx.x;
    unsigned int v = (tid < SCAN_BLOCKS) ? bsums[tid] : 0u;
    s[tid] = v;
    __syncthreads();
    for (int off = 1; off < 256; off <<= 1) {
        unsigned int t = (tid >= off) ? s[tid - off] : 0u;
        __syncthreads();
        s[tid] += t;
        __syncthreads();
    }
    if (tid < SCAN_BLOCKS) bsums[tid] = s[tid] - v;
}

__global__ void scanC_kernel(unsigned int* __restrict__ edge_off, const unsigned int* __restrict__ bsums,
                             unsigned int* __restrict__ cursor) {
    int i = blockIdx.x * 256 + threadIdx.x;
    if (i >= N_EDGES) return;
    unsigned int o = edge_off[i] + bsums[i >> 10];
    edge_off[i] = o;
    cursor[i] = o;
}

// 8 incidences/thread: 8 independent atomic returns in flight (hide far-atomic latency)
__global__ void bucket_kernel(const int* __restrict__ V, const int* __restrict__ E,
                              unsigned int* __restrict__ cursor,
                              uint2* __restrict__ vj, unsigned int* __restrict__ pos) {
    unsigned int base = blockIdx.x * 2048 + threadIdx.x;
    int ev[8], vv[8];
    unsigned int pp[8];
    #pragma unroll
    for (int c = 0; c < 8; ++c) {
        unsigned int j = base + 256u * c;
        if (j < NNZ) { ev[c] = E[j]; vv[c] = V[j]; }
    }
    #pragma unroll
    for (int c = 0; c < 8; ++c) {
        unsigned int j = base + 256u * c;
        if (j < NNZ) pp[c] = atomicAdd(&cursor[ev[c]], 1u);
    }
    #pragma unroll
    for (int c = 0; c < 8; ++c) {
        unsigned int j = base + 256u * c;
        if (j < NNZ) {
            vj[pp[c]] = make_uint2((unsigned int)vv[c], j);
            pos[j] = pp[c];
        }
    }
}

// ---------------- fused per-edge mean + per-incidence MLP (f32, CSR-order writes) ----------------
__global__ void edge_logit_kernel(const uint2* __restrict__ vj,
                                  const unsigned int* __restrict__ edge_off,
                                  const unsigned int* __restrict__ edge_cnt,
                                  const float2* __restrict__ p_ab2,
                                  const float* __restrict__ b1, const float* __restrict__ W2,
                                  const float* __restrict__ b2,
                                  float* __restrict__ probs_b, float* __restrict__ o_ep) {
    __shared__ float sa[4][32 * 32];   // 16 KB: [wave][slot i][k]
    __shared__ float slog[4][32];      // per-incidence logits
    int e = blockIdx.x * 4 + (threadIdx.x >> 6);
    if (e >= N_EDGES) return;
    int w    = threadIdx.x >> 6;
    int lane = threadIdx.x & 63;
    int k    = lane & 31;
    unsigned int half = (unsigned int)(lane >> 5);

    unsigned int off = edge_off[e];
    unsigned int deg = edge_cnt[e];
    unsigned int mind = deg < 32u ? deg : 32u;

    // coalesced member-id preload (lanes 0..mind-1)
    unsigned int myv = ((unsigned int)lane < mind) ? vj[off + lane].x : 0u;

    float bacc = 0.f;
    for (unsigned int i = half; i < mind; i += 2u) {
        unsigned int v = (unsigned int)__shfl((int)myv, (int)i, 64);
        float2 r = p_ab2[(size_t)v * 32u + k];
        sa[w][i * 32 + k] = r.x;
        bacc += r.y;
    }
    for (unsigned int i = 32u + half; i < deg; i += 2u) {   // deg>32 tail: b only
        unsigned int v = vj[off + i].x;
        bacc += p_ab2[(size_t)v * 32u + k].y;
    }

    float cc  = (float)(deg > 1u ? deg : 1u);
    float emk = (bacc + __shfl_xor(bacc, 32)) / cc + b1[k];
    float w2k = W2[k];
    float b2v = b2[0];
    float prsum = 0.f;

    for (unsigned int i = half; i < mind; i += 2u) {
        float hk = sa[w][i * 32 + k] + emk;
        hk = hk > 0.f ? hk : 0.f;
        float t = hk * w2k;
        #pragma unroll
        for (int o = 16; o > 0; o >>= 1) t += __shfl_down(t, o, 32);
        if (k == 0) slog[w][i] = t;
    }
    // vectorized epilogue: lane i <-> incidence i (same wave; LDS ops in order)
    if ((unsigned int)lane < mind) {
        float pr = 1.f / (1.f + __expf(-(slog[w][lane] + b2v)));
        probs_b[off + lane] = pr;      // coalesced
        prsum = pr;
    }
    for (unsigned int i = 32u + half; i < deg; i += 2u) {   // deg>32 tail: a from global
        unsigned int v = vj[off + i].x;
        float hk = p_ab2[(size_t)v * 32u + k].x + emk;
        hk = hk > 0.f ? hk : 0.f;
        float t = hk * w2k;
        #pragma unroll
        for (int o = 16; o > 0; o >>= 1) t += __shfl_down(t, o, 32);
        if (k == 0) {
            float pr = 1.f / (1.f + __expf(-(t + b2v)));
            probs_b[off + i] = pr;
            prsum += pr;
        }
    }
    #pragma unroll
    for (int o = 32; o > 0; o >>= 1) prsum += __shfl_down(prsum, o, 64);
    if (lane == 0) o_ep[e] = prsum / cc;
}

// ---------------- 2-level radix histogram on f32 keys ----------------
__global__ void hist1_kernel(const float* __restrict__ probs_b, unsigned int* __restrict__ hist) {
    __shared__ unsigned int lh[2048];
    for (int t = threadIdx.x; t < 2048; t += 256) lh[t] = 0;
    __syncthreads();
    for (unsigned int i = blockIdx.x * 256 + threadIdx.x; i < NNZ; i += gridDim.x * 256) {
        unsigned int key = __float_as_uint(probs_b[i]);
        atomicAdd(&lh[key >> 21], 1u);
    }
    __syncthreads();
    for (int t = threadIdx.x; t < 2048; t += 256)
        if (lh[t]) atomicAdd(&hist[t], lh[t]);
}

__global__ void hist2_kernel(const float* __restrict__ probs_b, const SelState* __restrict__ st,
                             unsigned int* __restrict__ hist) {
    __shared__ unsigned int lh[2048];
    for (int t = threadIdx.x; t < 2048; t += 256) lh[t] = 0;
    __syncthreads();
    unsigned int B1 = st->B1;
    for (unsigned int i = blockIdx.x * 256 + threadIdx.x; i < NNZ; i += gridDim.x * 256) {
        unsigned int key = __float_as_uint(probs_b[i]);
        if ((key >> 21) == B1) atomicAdd(&lh[(key >> 10) & 2047u], 1u);
    }
    __syncthreads();
    for (int t = threadIdx.x; t < 2048; t += 256)
        if (lh[t]) atomicAdd(&hist[2048 + t], lh[t]);
}

// which=0: select bucket B1 at rank K_KEEP; which=1: select B2 at rank rem1, set band edges
__global__ void scan_sel_kernel(const unsigned int* __restrict__ hist, SelState* __restrict__ st, int which) {
    __shared__ unsigned int csum[256];
    int t = threadIdx.x;
    unsigned int target = (which == 0) ? (unsigned int)K_KEEP : st->rem1;
    const unsigned int* h = hist + (which ? 2048 : 0);
    unsigned int b[8];
    unsigned int s = 0;
    #pragma unroll
    for (int i = 0; i < 8; ++i) { b[i] = h[t * 8 + i]; s += b[i]; }
    csum[t] = s;
    __syncthreads();
    for (int off = 1; off < 256; off <<= 1) {
        unsigned int v = (t + off < 256) ? csum[t + off] : 0u;
        __syncthreads();
        csum[t] += v;
        __syncthreads();
    }
    unsigned int above = csum[t] - s;       // sum over chunks > t
    if (above < target && target <= above + s) {
        unsigned int rem = target - above;
        unsigned int cum = 0;
        #pragma unroll
        for (int i = 7; i >= 0; --i) {
            if (rem <= cum + b[i]) {
                unsigned int bin = (unsigned int)(t * 8 + i);
                if (which == 0) { st->B1 = bin; st->rem1 = rem - cum; }
                else {
                    unsigned int P = (st->B1 << 21) | (bin << 10);
                    st->lo_edge = __uint_as_float(P) - DELTA;
                    st->hi_edge = __uint_as_float(P + 1024u) + DELTA;
                }
                break;
            }
            cum += b[i];
        }
    }
}

// two-phase fused n_hi count + band append: 1024 grid-stride blocks, 2 global atomics/block
__global__ void bandsel_kernel(const float* __restrict__ probs_b, const int* __restrict__ E,
                               const uint2* __restrict__ vj,
                               SelState* __restrict__ st,
                               unsigned int* __restrict__ band_p, unsigned int* __restrict__ band_j,
                               unsigned int* __restrict__ band_e, unsigned int* __restrict__ band_v) {
    __shared__ unsigned int whi[4], wband[4];
    __shared__ unsigned int sbase, scur;
    float hi = st->hi_edge, lo = st->lo_edge;
    // phase A: local counts
    unsigned int nhi = 0, nband = 0;
    for (unsigned int p = blockIdx.x * 256 + threadIdx.x; p < NNZ; p += gridDim.x * 256) {
        float pk = probs_b[p];
        if (pk > hi) nhi++;
        else if (pk >= lo) nband++;
    }
    #pragma unroll
    for (int o = 32; o > 0; o >>= 1) {
        nhi   += __shfl_down(nhi, o);
        nband += __shfl_down(nband, o);
    }
    if ((threadIdx.x & 63) == 0) { whi[threadIdx.x >> 6] = nhi; wband[threadIdx.x >> 6] = nband; }
    __syncthreads();
    if (threadIdx.x == 0) {
        unsigned int th = whi[0] + whi[1] + whi[2] + whi[3];
        unsigned int tb = wband[0] + wband[1] + wband[2] + wband[3];
        if (th) atomicAdd(&st->n_hi, th);
        sbase = tb ? atomicAdd(&st->band_n, tb) : 0u;
        scur = 0;
    }
    __syncthreads();
    // phase B: append via LDS cursor (order within block arbitrary; selection is key-based)
    for (unsigned int p = blockIdx.x * 256 + threadIdx.x; p < NNZ; p += gridDim.x * 256) {
        float pk = probs_b[p];
        if (pk <= hi && pk >= lo) {
            unsigned int s = sbase + atomicAdd(&scur, 1u);
            if (s < BANDCAP) {
                uint2 t = vj[p];
                band_p[s] = p;
                band_j[s] = t.y;
                band_e[s] = (unsigned int)E[t.y];
                band_v[s] = t.x;
            }
        }
    }
}

// exact f64 recompute for band members; W1 staged in LDS
__global__ void rescue_kernel(const uint2* __restrict__ vj,
                              const unsigned int* __restrict__ edge_off,
                              const unsigned int* __restrict__ edge_cnt,
                              const float* __restrict__ x, const float* __restrict__ W1,
                              const float* __restrict__ b1, const float* __restrict__ W2,
                              const float* __restrict__ b2,
                              const unsigned int* __restrict__ band_e,
                              const unsigned int* __restrict__ band_v,
                              const SelState* __restrict__ st,
                              unsigned long long* __restrict__ band_key) {
    unsigned int n = st->band_n; if (n > BANDCAP) n = BANDCAP;
    if (blockIdx.x * 8 >= n) return;
    __shared__ float sW[128 * 32];
    for (int t = threadIdx.x; t < 128 * 32; t += 256) sW[t] = W1[t];
    __syncthreads();
    unsigned int g = blockIdx.x * 8 + (threadIdx.x >> 5);
    if (g >= n) return;
    int k = threadIdx.x & 31;
    unsigned int v = band_v[g];
    unsigned int e = band_e[g];
    unsigned int off = edge_off[e];
    unsigned int deg = edge_cnt[e];

    const float* xv = x + (size_t)v * 64u;
    double a = 0.0;
    #pragma unroll 8
    for (int d = 0; d < 64; ++d) a += (double)xv[d] * (double)sW[d * 32 + k];
    double bsum = 0.0;
    for (unsigned int m = off; m < off + deg; ++m) {
        const float* xm = x + (size_t)vj[m].x * 64u;
        double acc = 0.0;
        #pragma unroll 8
        for (int d = 0; d < 64; ++d) acc += (double)xm[d] * (double)sW[(64 + d) * 32 + k];
        bsum += acc;
    }
    double cc = (double)(deg > 1u ? deg : 1u);
    double h = a + bsum / cc + (double)b1[k];
    h = h > 0.0 ? h : 0.0;
    double t = h * (double)W2[k];
    #pragma unroll
    for (int o = 16; o > 0; o >>= 1) t += __shfl_down(t, o, 32);
    if (k == 0) {
        double pr = 1.0 / (1.0 + exp(-(t + (double)b2[0])));
        band_key[g] = (unsigned long long)__double_as_longlong(pr);
    }
}

// ---------------- O(n) band selection: 2-level hist on monotone u32 map ----------------
__global__ void bhist1_kernel(const unsigned long long* __restrict__ band_key,
                              const SelState* __restrict__ st, unsigned int* __restrict__ hist) {
    __shared__ unsigned int lh[2048];
    for (int t = threadIdx.x; t < 2048; t += 256) lh[t] = 0;
    __syncthreads();
    unsigned int n = st->band_n; if (n > BANDCAP) n = BANDCAP;
    float lo = st->lo_edge;
    for (unsigned int i = blockIdx.x * 256 + threadIdx.x; i < n; i += gridDim.x * 256) {
        unsigned int u = band_u32(__longlong_as_double((long long)band_key[i]), lo);
        atomicAdd(&lh[u >> 21], 1u);
    }
    __syncthreads();
    for (int t = threadIdx.x; t < 2048; t += 256)
        if (lh[t]) atomicAdd(&hist[4096 + t], lh[t]);
}

__global__ void bhist2_kernel(const unsigned long long* __restrict__ band_key,
                              const SelState* __restrict__ st, unsigned int* __restrict__ hist) {
    __shared__ unsigned int lh[2048];
    for (int t = threadIdx.x; t < 2048; t += 256) lh[t] = 0;
    __syncthreads();
    unsigned int n = st->band_n; if (n > BANDCAP) n = BANDCAP;
    float lo = st->lo_edge;
    unsigned int bB1 = st->bB1;
    for (unsigned int i = blockIdx.x * 256 + threadIdx.x; i < n; i += gridDim.x * 256) {
        unsigned int u = band_u32(__longlong_as_double((long long)band_key[i]), lo);
        if ((u >> 21) == bB1) atomicAdd(&lh[(u >> 10) & 2047u], 1u);
    }
    __syncthreads();
    for (int t = threadIdx.x; t < 2048; t += 256)
        if (lh[t]) atomicAdd(&hist[6144 + t], lh[t]);
}

// which=0: bucket bB1 at rank (K_KEEP - n_hi); which=1: bucket bB2 at rank brem1 -> bU0, brem2
__global__ void bscan_kernel(const unsigned int* __restrict__ hist, SelState* __restrict__ st, int which) {
    __shared__ unsigned int csum[256];
    int t = threadIdx.x;
    unsigned int target = (which == 0) ? ((unsigned int)K_KEEP - st->n_hi) : st->brem1;
    const unsigned int* h = hist + (which ? 6144 : 4096);
    unsigned int b[8];
    unsigned int s = 0;
    #pragma unroll
    for (int i = 0; i < 8; ++i) { b[i] = h[t * 8 + i]; s += b[i]; }
    csum[t] = s;
    __syncthreads();
    for (int off = 1; off < 256; off <<= 1) {
        unsigned int v = (t + off < 256) ? csum[t + off] : 0u;
        __syncthreads();
        csum[t] += v;
        __syncthreads();
    }
    unsigned int above = csum[t] - s;
    if (above < target && target <= above + s) {
        unsigned int rem = target - above;
        unsigned int cum = 0;
        #pragma unroll
        for (int i = 7; i >= 0; --i) {
            if (rem <= cum + b[i]) {
                unsigned int bin = (unsigned int)(t * 8 + i);
                if (which == 0) { st->bB1 = bin; st->brem1 = rem - cum; }
                else            { st->bU0 = (st->bB1 << 21) | (bin << 10); st->brem2 = rem - cum; }
                break;
            }
            cum += b[i];
        }
    }
}

// mark u >= bU0+1024 selected; collect tie bucket [bU0, bU0+1024)
__global__ void btie_kernel(const unsigned long long* __restrict__ band_key,
                            const unsigned int* __restrict__ band_j,
                            const unsigned int* __restrict__ band_p,
                            SelState* __restrict__ st, unsigned char* __restrict__ flag,
                            unsigned long long* __restrict__ tie_k,
                            unsigned int* __restrict__ tie_j, unsigned int* __restrict__ tie_p) {
    unsigned int n = st->band_n; if (n > BANDCAP) n = BANDCAP;
    unsigned int i = blockIdx.x * 256 + threadIdx.x;
    if (i >= n) return;
    float lo = st->lo_edge;
    unsigned int U0 = st->bU0;
    unsigned long long key = band_key[i];
    unsigned int u = band_u32(__longlong_as_double((long long)key), lo);
    if (u >= U0 + 1024u) {
        flag[band_p[i]] = 2u;
    } else if (u >= U0) {
        unsigned int s = atomicAdd(&st->tie_n, 1u);
        if (s < TIECAP) { tie_k[s] = key; tie_j[s] = band_j[i]; tie_p[s] = band_p[i]; }
    }
}

// exact rank inside the (tiny) tie bucket by (key desc, j asc); take first brem2
__global__ void btierank_kernel(const unsigned long long* __restrict__ tie_k,
                                const unsigned int* __restrict__ tie_j,
                                const unsigned int* __restrict__ tie_p,
                                const SelState* __restrict__ st, unsigned char* __restrict__ flag) {
    unsigned int n = st->tie_n; if (n > TIECAP) n = TIECAP;
    unsigned int need = st->brem2;
    for (unsigned int i = threadIdx.x; i < n; i += 256) {
        unsigned long long ki = tie_k[i];
        unsigned int ji = tie_j[i];
        unsigned int r = 0;
        for (unsigned int q = 0; q < n; ++q) {
            unsigned long long kq = tie_k[q];
            if (kq > ki || (kq == ki && tie_j[q] < ji)) r++;
        }
        if (r < need) flag[tie_p[i]] = 2u;
    }
}

// j-order coalesced outputs; hard bit computed inline from gathered probs/flag
__global__ void out_kernel(const float* __restrict__ probs_b, const unsigned char* __restrict__ flag,
                           const unsigned int* __restrict__ pos, const SelState* __restrict__ st,
                           float* __restrict__ o_probs, float* __restrict__ o_soft, float* __restrict__ o_hard) {
    unsigned int j = blockIdx.x * 256 + threadIdx.x;
    if (j >= NNZ) return;
    float hi = st->hi_edge;
    unsigned int p = pos[j];
    float pk = probs_b[p];
    float hb = (pk > hi || flag[p] == 2u) ? 1.f : 0.f;
    o_probs[j] = pk;
    o_soft[j]  = hb;
    o_hard[j]  = hb;
}

// per-edge: edge_soft / edge_hard recomputed from CSR-coalesced probs/flag
__global__ void edge_out_kernel(const float* __restrict__ probs_b, const unsigned char* __restrict__ flag,
                                const unsigned int* __restrict__ edge_off,
                                const unsigned int* __restrict__ edge_cnt,
                                const SelState* __restrict__ st,
                                float* __restrict__ o_es, float* __restrict__ o_eh) {
    unsigned int e = blockIdx.x * 256 + threadIdx.x;
    if (e >= N_EDGES) return;
    float hi = st->hi_edge;
    unsigned int off = edge_off[e], deg = edge_cnt[e];
    unsigned int cnt = 0;
    for (unsigned int i = 0; i < deg; ++i)
        cnt += (probs_b[off + i] > hi || flag[off + i] == 2u) ? 1u : 0u;
    float cc = (float)(deg > 1u ? deg : 1u);
    o_es[e] = (float)cnt / cc;
    o_eh[e] = cnt ? 1.f : 0.f;
}

extern "C" void kernel_launch(void* const* d_in, const int* in_sizes, int n_in,
                              void* d_out, int out_size, void* d_ws, size_t ws_size,
                              hipStream_t stream) {
    const float* x  = (const float*)d_in[0];
    const int*   V  = (const int*)d_in[1];
    const int*   E  = (const int*)d_in[2];
    const float* W1 = (const float*)d_in[3];
    const float* b1 = (const float*)d_in[4];
    const float* W2 = (const float*)d_in[5];
    const float* b2 = (const float*)d_in[6];

    float* out     = (float*)d_out;
    float* o_probs = out;
    float* o_soft  = out + NNZ;
    float* o_hard  = out + 2 * (size_t)NNZ;
    float* o_ep    = out + 3 * (size_t)NNZ;
    float* o_es    = out + 3 * (size_t)NNZ + N_EDGES;
    float* o_eh    = out + 3 * (size_t)NNZ + 2 * (size_t)N_EDGES;

    char* w = (char*)d_ws;
    float2*             p_ab2    = (float2*)(w + OFF_PAB);
    float*              probs_b  = (float*)(w + OFF_PB32);
    uint2*              vj       = (uint2*)(w + OFF_VJ);
    unsigned int*       pos      = (unsigned int*)(w + OFF_POS);
    unsigned int*       edge_off = (unsigned int*)(w + OFF_EOFF);
    unsigned int*       cursor   = (unsigned int*)(w + OFF_CUR);
    unsigned int*       bsums    = (unsigned int*)(w + OFF_BS);
    unsigned int*       band_p   = (unsigned int*)(w + OFF_BANDP);
    unsigned int*       band_j   = (unsigned int*)(w + OFF_BANDJ);
    unsigned int*       band_e   = (unsigned int*)(w + OFF_BANDE);
    unsigned int*       band_v   = (unsigned int*)(w + OFF_BANDV);
    unsigned long long* band_key = (unsigned long long*)(w + OFF_BANDK);
    unsigned long long* tie_k    = (unsigned long long*)(w + OFF_TIEK);
    unsigned int*       tie_j    = (unsigned int*)(w + OFF_TIEJ);
    unsigned int*       tie_p    = (unsigned int*)(w + OFF_TIEP);
    unsigned char*      flag     = (unsigned char*)(w + OFF_FLAG);
    unsigned int*       edge_cnt = (unsigned int*)(w + OFF_ECNT);
    unsigned int*       hist     = (unsigned int*)(w + OFF_HIST);
    SelState*           st       = (SelState*)(w + OFF_ST);

    hipMemsetAsync(w + ZERO_OFF, 0, ZERO_LEN, stream);

    proj_kernel<<<(N_NODES + 7) / 8, 256, 0, stream>>>(x, W1, p_ab2);

    count_kernel<<<(NNZ + 255) / 256, 256, 0, stream>>>(E, edge_cnt);
    scanA_kernel<<<SCAN_BLOCKS, 256, 0, stream>>>(edge_cnt, edge_off, bsums);
    scanB_kernel<<<1, 256, 0, stream>>>(bsums);
    scanC_kernel<<<(N_EDGES + 255) / 256, 256, 0, stream>>>(edge_off, bsums, cursor);
    bucket_kernel<<<(NNZ + 2047) / 2048, 256, 0, stream>>>(V, E, cursor, vj, pos);

    edge_logit_kernel<<<(N_EDGES + 3) / 4, 256, 0, stream>>>(vj, edge_off, edge_cnt,
                                                             p_ab2, b1, W2, b2, probs_b, o_ep);

    hist1_kernel<<<1024, 256, 0, stream>>>(probs_b, hist);
    scan_sel_kernel<<<1, 256, 0, stream>>>(hist, st, 0);
    hist2_kernel<<<1024, 256, 0, stream>>>(probs_b, st, hist);
    scan_sel_kernel<<<1, 256, 0, stream>>>(hist, st, 1);

    bandsel_kernel<<<1024, 256, 0, stream>>>(probs_b, E, vj, st,
                                             band_p, band_j, band_e, band_v);
    rescue_kernel<<<BANDCAP / 8, 256, 0, stream>>>(vj, edge_off, edge_cnt, x, W1, b1, W2, b2,
                                                   band_e, band_v, st, band_key);

    bhist1_kernel<<<64, 256, 0, stream>>>(band_key, st, hist);
    bscan_kernel<<<1, 256, 0, stream>>>(hist, st, 0);
    bhist2_kernel<<<64, 256, 0, stream>>>(band_key, st, hist);
    bscan_kernel<<<1, 256, 0, stream>>>(hist, st, 1);
    btie_kernel<<<BANDCAP / 256, 256, 0, stream>>>(band_key, band_j, band_p, st, flag,
                                                   tie_k, tie_j, tie_p);
    btierank_kernel<<<1, 256, 0, stream>>>(tie_k, tie_j, tie_p, st, flag);

    out_kernel<<<(NNZ + 255) / 256, 256, 0, stream>>>(probs_b, flag, pos, st, o_probs, o_soft, o_hard);
    edge_out_kernel<<<(N_EDGES + 255) / 256, 256, 0, stream>>>(probs_b, flag, edge_off, edge_cnt, st,
                                                               o_es, o_eh);
}